// Round 11
// baseline (5124.877 us; speedup 1.0000x reference)
//
#include <hip/hip_runtime.h>

// Sudoku solver: ONE kernel, zero grid syncs. 256 blocks x 1024 threads.
// Each block owns 2 boards; thread (half = tid>>9, j = tid&511) computes
// output column j for board `half` (16 waves/block = 4 waves/SIMD).
// Round-11 vs round-9 (283us verified best; VGPR is compiler-capped at 64,
// so register-prefetch deepening is dead — rounds 5/8/10 all spilled):
//  - TRANSPOSED activation layout h[slot][k] (was h[k][slot]): one
//    ds_read_b128 now fetches 4 k's for one slot. DS-instr count per layer:
//    CNT=4 same, CNT=3 -25%, CNT=2 -50%, CNT=1 -75% (iters 2-4 of the
//    solver). Reads remain wave-uniform broadcasts; writes become stride-1
//    scalars (conflict-free). Per-accumulator ascending-k order preserved.
//  - CROSS-BARRIER weight prefetch: next layer's first 8-weight group loads
//    in the dead odd-slot of the last ping-pong stage, staying in flight
//    across the layer barrier (no vmcnt drain at the boundary).
// Tripwire: WRITE_SIZE must stay ~3MB (no spill); else revert.

#define NN 81
#define ND 9
#define BND 729            // NN*ND
#define HD 512
#define BTSZ 512
#define XTOT (BTSZ * BND)  // 373248
#define NBLK 256           // 2 boards per block
#define TPB 1024

struct Params {
  const float* x_in;
  const float* W[10];
  const float* Bb[10];
  const int* n_it;
  float* xpred;
  float* xcur;
};

// FMA over 8 consecutive k for one board's CNT slots, transposed layout.
// hrow = hin + half4*HD; slot e's values at hrow[e*HD + k].
template <int CNT>
__device__ __forceinline__ void fma8T(const float* __restrict__ hrow,
                                      int kbase, const float (&w)[8],
                                      float (&a)[CNT]) {
#pragma unroll
  for (int h2 = 0; h2 < 2; ++h2) {
    const int k0 = kbase + h2 * 4;
    float hf[CNT][4];
#pragma unroll
    for (int e = 0; e < CNT; ++e) {
      const float4 hv = *(const float4*)&hrow[e * HD + k0];
      hf[e][0] = hv.x; hf[e][1] = hv.y; hf[e][2] = hv.z; hf[e][3] = hv.w;
    }
#pragma unroll
    for (int kk = 0; kk < 4; ++kk) {
#pragma unroll
      for (int e = 0; e < CNT; ++e) a[e] += hf[e][kk] * w[h2 * 4 + kk];
    }
  }
}

// layers 2..9: GEMV, 8-deep ping-pong weight prefetch (16 VGPRs) with
// cross-barrier hoist of the next layer's first group.
template <int CNT>
__device__ __forceinline__ void run_layers(const Params& p, int j, int half4,
                                           float* bufA, float* bufB) {
  const float* hin = bufA;
  float* hout = bufB;
  const float* __restrict__ wp = p.W[1] + j;
  float wA[8], wB[8];
#pragma unroll
  for (int kk = 0; kk < 8; ++kk) wA[kk] = wp[kk * HD];  // layer 2, k 0..7
  for (int l = 1; l <= 8; ++l) {
    const float* __restrict__ hrow = hin + half4 * HD;
    float a[CNT];
#pragma unroll
    for (int e = 0; e < CNT; ++e) a[e] = 0.f;
#pragma unroll
    for (int g = 0; g < 16; g += 2) {
      // even stage: prefetch group g+1 into wB, FMA group g from wA
#pragma unroll
      for (int kk = 0; kk < 8; ++kk) wB[kk] = wp[((g + 1) * 8 + kk) * HD];
      fma8T<CNT>(hrow, g * 8, wA, a);
      // odd stage: prefetch group g+2 into wA (or NEXT LAYER's group 0,
      // issued before the barrier so it stays in flight across it)
      if (g + 2 < 16) {
#pragma unroll
        for (int kk = 0; kk < 8; ++kk) wA[kk] = wp[((g + 2) * 8 + kk) * HD];
      } else if (l < 8) {
        wp = p.W[l + 1] + j;
#pragma unroll
        for (int kk = 0; kk < 8; ++kk) wA[kk] = wp[kk * HD];
      }
      fma8T<CNT>(hrow, (g + 1) * 8, wB, a);
    }
    const float bj = p.Bb[l][j];
    float o[CNT];
#pragma unroll
    for (int e = 0; e < CNT; ++e) o[e] = fmaxf(a[e] + bj, 0.f);
#pragma unroll
    for (int e = 0; e < CNT; ++e) hout[(half4 + e) * HD + j] = o[e];
    __syncthreads();
    const float* t = hin; hin = hout; hout = (float*)t;
  }
}

__global__ __launch_bounds__(TPB, 4) void fused(Params p) {
  const int tid = threadIdx.x;
  const int bid = blockIdx.x;
  const int b0 = bid * 2;
  const int half = tid >> 9;       // board within block
  const int j = tid & 511;         // output column
  const int half4 = half * 4;

  __shared__ __align__(16) float hbufA[8 * HD];  // 16 KB ping  h[slot][k]
  __shared__ __align__(16) float hbufB[8 * HD];  // 16 KB pong
  __shared__ __align__(16) float W10s[HD * ND];  // 18 KB
  __shared__ float xs[2][BND + 3];
  __shared__ float fs[2][4][28];
  __shared__ float sMax[8];
  __shared__ int sPos[8];
  __shared__ int ef[2][NN + 7];
  __shared__ int lst[2][4];
  __shared__ int eCnt[2];

  for (int i = tid; i < HD * ND; i += TPB) W10s[i] = p.W[9][i];
  for (int bd = 0; bd < 2; ++bd)
    for (int i = tid; i < BND; i += TPB) {
      const float v = p.x_in[(b0 + bd) * BND + i];
      xs[bd][i] = v;
      p.xpred[(b0 + bd) * BND + i] = v;
    }
  const int nIters = p.n_it[0];
  __syncthreads();

  for (int it = 0; it < 4; ++it) {
    if (it >= nIters) break;

    // ---- empty flags ----
    if (tid < 2 * NN) {
      const int bd = tid / NN, q = tid - bd * NN;
      float s = 0.f;
#pragma unroll
      for (int n = 0; n < ND; ++n) s += xs[bd][q * ND + n];
      ef[bd][q] = (s == 0.0f) ? 1 : 0;
    }
    __syncthreads();
    if (tid < 2) {
      int c = 0;
      for (int q = 0; q < NN; ++q)
        if (ef[tid][q] && c < 4) lst[tid][c++] = q;  // ascending q
      eCnt[tid] = c;
    }
    __syncthreads();

    // ---- features (zero for inactive slots) ----
    {
      const int sl = tid >> 5, u = tid & 31;
      if (sl < 8) {
        const int bd = sl >> 2, e = sl & 3;
        if (u < 28) fs[bd][e][u] = 0.0f;
        if (u < 27 && e < eCnt[bd]) {
          const int q = lst[bd][e], t = u / 9, n = u - t * 9;
          const int r = q / 9, cl = q - r * 9;
          float s = 0.f;
          if (t == 0) {
            for (int i = 0; i < 9; ++i) s += xs[bd][(r * 9 + i) * ND + n];
          } else if (t == 1) {
            for (int i = 0; i < 9; ++i) s += xs[bd][(i * 9 + cl) * ND + n];
          } else {
            const int br = (r / 3) * 3, bc = (cl / 3) * 3;
            for (int i = 0; i < 3; ++i)
              for (int jj = 0; jj < 3; ++jj)
                s += xs[bd][((br + i) * 9 + bc + jj) * ND + n];
          }
          fs[bd][e][u] = s;
        }
      }
    }
    __syncthreads();

    // ---- layer 1: bias + ascending-i chain for own board's 4 slots ----
    {
      float a[4];
      const float b1 = p.Bb[0][j];
#pragma unroll
      for (int e = 0; e < 4; ++e) a[e] = b1;
      const float* __restrict__ w1p = p.W[0] + j;
      for (int i = 0; i < 27; ++i) {
        const float w = w1p[i * HD];
#pragma unroll
        for (int e = 0; e < 4; ++e) a[e] += fs[half][e][i] * w;
      }
#pragma unroll
      for (int e = 0; e < 4; ++e)
        hbufA[(half4 + e) * HD + j] = fmaxf(a[e], 0.f);
    }
    __syncthreads();

    // ---- layers 2..9, specialized on active slot count ----
    const int cm = max(eCnt[0], eCnt[1]);
    if (cm == 4) run_layers<4>(p, j, half4, hbufA, hbufB);
    else if (cm == 3) run_layers<3>(p, j, half4, hbufA, hbufB);
    else if (cm == 2) run_layers<2>(p, j, half4, hbufA, hbufB);
    else if (cm == 1) run_layers<1>(p, j, half4, hbufA, hbufB);
    // after 8 layers (even # of swaps), h9 is in hbufA

    // ---- final: layer 10 + softmax + per-slot max (wave per slot) ----
    if (cm > 0) {
      const int s = tid >> 6, lane = tid & 63;
      if (s < 8) {
        const int bd = s >> 2, e = s & 3;
        if (e < eCnt[bd]) {
          float acc[ND];
#pragma unroll
          for (int jj = 0; jj < ND; ++jj) acc[jj] = 0.f;
#pragma unroll
          for (int i = 0; i < 8; ++i) {
            const int k = lane + 64 * i;
            const float hvv = hbufA[s * HD + k];
#pragma unroll
            for (int jj = 0; jj < ND; ++jj) acc[jj] += hvv * W10s[k * ND + jj];
          }
#pragma unroll
          for (int jj = 0; jj < ND; ++jj) {
#pragma unroll
            for (int off = 32; off >= 1; off >>= 1)
              acc[jj] += __shfl_xor(acc[jj], off, 64);
          }
          if (lane == 0) {
            float lgt[ND];
#pragma unroll
            for (int jj = 0; jj < ND; ++jj) lgt[jj] = acc[jj] + p.Bb[9][jj];
            float mx = lgt[0];
            for (int jj = 1; jj < ND; ++jj) mx = fmaxf(mx, lgt[jj]);
            float e2[ND], sm = 0.f;
            for (int jj = 0; jj < ND; ++jj) {
              e2[jj] = expf(lgt[jj] - mx);
              sm += e2[jj];
            }
            float pr[ND];
            for (int jj = 0; jj < ND; ++jj) pr[jj] = e2[jj] / sm;
            const int q = lst[bd][e];
            float best = pr[0];
            int pos = 0;
            for (int jj = 1; jj < ND; ++jj)
              if (pr[jj] > best) { best = pr[jj]; pos = jj; }  // first-index tie
            float* dst = p.xpred + ((b0 + bd) * NN + q) * ND;
            for (int jj = 0; jj < ND; ++jj) dst[jj] = pr[jj];
            sMax[s] = best;
            sPos[s] = pos;
          }
        }
      }
    }
    __syncthreads();

    // ---- update: most confident slot per board (strict >, lowest q) ----
    if (tid < 2) {
      const int c = eCnt[tid];
      if (c > 0) {
        float best = sMax[tid * 4];
        int bj = 0;
        for (int jj = 1; jj < c; ++jj) {
          const float v = sMax[tid * 4 + jj];
          if (v > best) { best = v; bj = jj; }
        }
        const int q = lst[tid][bj], pos = sPos[tid * 4 + bj];
        xs[tid][q * ND + pos] = 1.0f;
      }
    }
    __syncthreads();
  }

  // ---- write final board state (output 2) ----
  for (int bd = 0; bd < 2; ++bd)
    for (int i = tid; i < BND; i += TPB)
      p.xcur[(b0 + bd) * BND + i] = xs[bd][i];
}

extern "C" void kernel_launch(void* const* d_in, const int* in_sizes, int n_in,
                              void* d_out, int out_size, void* d_ws, size_t ws_size,
                              hipStream_t stream) {
  Params prm;
  prm.x_in = (const float*)d_in[0];
  for (int i = 0; i < 10; ++i) {
    prm.W[i] = (const float*)d_in[2 + 2 * i];
    prm.Bb[i] = (const float*)d_in[3 + 2 * i];
  }
  prm.n_it = (const int*)d_in[22];
  prm.xpred = (float*)d_out;
  prm.xcur = prm.xpred + XTOT;

  fused<<<dim3(NBLK), dim3(TPB), 0, stream>>>(prm);
}

// Round 12
// 282.372 us; speedup vs baseline: 18.1494x; 18.1494x over previous
//
#include <hip/hip_runtime.h>

// Sudoku solver: ONE kernel, zero grid syncs. 256 blocks x 1024 threads.
// Each block owns 2 boards; thread (half = tid>>9, j = tid&511) computes
// output column j for board `half` (16 waves/block = 4 waves/SIMD).
// VERIFIED-BEST configuration (rounds 6/9: 283us). FINAL revert after four
// spill-killed probes (5/8/10/11) and two sync-killed probes (1/2):
//  - register prefetch beyond 8-deep (16 VGPRs): compiler pins VGPR=64,
//    spills to scratch (WRITE_SIZE 3MB -> 0.3-9.5GB)   [rounds 5/8/10/11]
//  - amdgpu_waves_per_eu(4,4) does NOT raise the allocator's budget [r10]
//  - transposed h[slot][k] LDS layout: raises live set -> spills   [r11]
//  - ReLU-sparsity k-skip: OOB + breaks cross-half L1 dedup        [r7]
//  - cross-block barriers (coop or hand-rolled): >= dispatch cost  [r1/r2]
// Roofline position: 256 blocks x 8.05MB weights x 4 iters = 8.25GB from L2
// in 283us = 29.2 TB/s = ~85-89% of the 34.5 TB/s L2 ceiling. The weight
// traffic is structural (every block needs all weights every iteration;
// 2 boards/block pinned by 512 boards / 256 CUs at TPB=1024 max).
// Residual gap = L2 latency at 32 layer boundaries, unhidable at VGPR=64.

#define NN 81
#define ND 9
#define BND 729            // NN*ND
#define HD 512
#define BTSZ 512
#define XTOT (BTSZ * BND)  // 373248
#define NBLK 256           // 2 boards per block
#define TPB 1024

struct Params {
  const float* x_in;
  const float* W[10];
  const float* Bb[10];
  const int* n_it;
  float* xpred;
  float* xcur;
};

// FMA over 8 consecutive k for one board's CNT slots.
// hin layout: h[k*8 + half4 + e]
template <int CNT>
__device__ __forceinline__ void fma8(const float* __restrict__ hin, int half4,
                                     int kbase, const float (&w)[8],
                                     float (&a)[CNT]) {
#pragma unroll
  for (int kk = 0; kk < 8; ++kk) {
    const int k = kbase + kk;
    if constexpr (CNT > 2) {
      const float4 h = *(const float4*)&hin[k * 8 + half4];
      const float hv[4] = {h.x, h.y, h.z, h.w};
#pragma unroll
      for (int e = 0; e < CNT; ++e) a[e] += hv[e] * w[kk];
    } else {
      const float2 h = *(const float2*)&hin[k * 8 + half4];
      const float hv[2] = {h.x, h.y};
#pragma unroll
      for (int e = 0; e < CNT; ++e) a[e] += hv[e] * w[kk];
    }
  }
}

// layers 2..9: GEMV with 8-deep ping-pong weight prefetch (16 VGPRs).
template <int CNT>
__device__ __forceinline__ void run_layers(const Params& p, int j, int half4,
                                           float* bufA, float* bufB) {
  const float* hin = bufA;
  float* hout = bufB;
  for (int l = 1; l <= 8; ++l) {
    const float* __restrict__ wp = p.W[l] + j;
    float a[CNT];
#pragma unroll
    for (int e = 0; e < CNT; ++e) a[e] = 0.f;
    float wA[8], wB[8];
#pragma unroll
    for (int kk = 0; kk < 8; ++kk) wA[kk] = wp[kk * HD];  // k 0..7
#pragma unroll
    for (int g = 0; g < 16; g += 2) {
      // even stage: prefetch group g+1, FMA group g (from wA)
#pragma unroll
      for (int kk = 0; kk < 8; ++kk) wB[kk] = wp[((g + 1) * 8 + kk) * HD];
      fma8<CNT>(hin, half4, g * 8, wA, a);
      // odd stage: prefetch group g+2, FMA group g+1 (from wB)
      if (g + 2 < 16) {
#pragma unroll
        for (int kk = 0; kk < 8; ++kk) wA[kk] = wp[((g + 2) * 8 + kk) * HD];
      }
      fma8<CNT>(hin, half4, (g + 1) * 8, wB, a);
    }
    const float bj = p.Bb[l][j];
    float o[4] = {0.f, 0.f, 0.f, 0.f};
#pragma unroll
    for (int e = 0; e < CNT; ++e) o[e] = fmaxf(a[e] + bj, 0.f);
    float4 v;
    v.x = o[0]; v.y = o[1]; v.z = o[2]; v.w = o[3];
    *(float4*)&hout[j * 8 + half4] = v;
    __syncthreads();
    const float* t = hin; hin = hout; hout = (float*)t;
  }
}

__global__ __launch_bounds__(TPB, 4) void fused(Params p) {
  const int tid = threadIdx.x;
  const int bid = blockIdx.x;
  const int b0 = bid * 2;
  const int half = tid >> 9;       // board within block
  const int j = tid & 511;         // output column
  const int half4 = half * 4;

  __shared__ __align__(16) float hbufA[HD * 8];  // 16 KB ping  h[k][bd][e]
  __shared__ __align__(16) float hbufB[HD * 8];  // 16 KB pong
  __shared__ __align__(16) float W10s[HD * ND];  // 18 KB
  __shared__ float xs[2][BND + 3];
  __shared__ float fs[2][4][28];
  __shared__ float sMax[8];
  __shared__ int sPos[8];
  __shared__ int ef[2][NN + 7];
  __shared__ int lst[2][4];
  __shared__ int eCnt[2];

  for (int i = tid; i < HD * ND; i += TPB) W10s[i] = p.W[9][i];
  for (int bd = 0; bd < 2; ++bd)
    for (int i = tid; i < BND; i += TPB) {
      const float v = p.x_in[(b0 + bd) * BND + i];
      xs[bd][i] = v;
      p.xpred[(b0 + bd) * BND + i] = v;
    }
  const int nIters = p.n_it[0];
  __syncthreads();

  for (int it = 0; it < 4; ++it) {
    if (it >= nIters) break;

    // ---- empty flags ----
    if (tid < 2 * NN) {
      const int bd = tid / NN, q = tid - bd * NN;
      float s = 0.f;
#pragma unroll
      for (int n = 0; n < ND; ++n) s += xs[bd][q * ND + n];
      ef[bd][q] = (s == 0.0f) ? 1 : 0;
    }
    __syncthreads();
    if (tid < 2) {
      int c = 0;
      for (int q = 0; q < NN; ++q)
        if (ef[tid][q] && c < 4) lst[tid][c++] = q;  // ascending q
      eCnt[tid] = c;
    }
    __syncthreads();

    // ---- features (zero for inactive slots) ----
    {
      const int sl = tid >> 5, u = tid & 31;
      if (sl < 8) {
        const int bd = sl >> 2, e = sl & 3;
        if (u < 28) fs[bd][e][u] = 0.0f;
        if (u < 27 && e < eCnt[bd]) {
          const int q = lst[bd][e], t = u / 9, n = u - t * 9;
          const int r = q / 9, cl = q - r * 9;
          float s = 0.f;
          if (t == 0) {
            for (int i = 0; i < 9; ++i) s += xs[bd][(r * 9 + i) * ND + n];
          } else if (t == 1) {
            for (int i = 0; i < 9; ++i) s += xs[bd][(i * 9 + cl) * ND + n];
          } else {
            const int br = (r / 3) * 3, bc = (cl / 3) * 3;
            for (int i = 0; i < 3; ++i)
              for (int jj = 0; jj < 3; ++jj)
                s += xs[bd][((br + i) * 9 + bc + jj) * ND + n];
          }
          fs[bd][e][u] = s;
        }
      }
    }
    __syncthreads();

    // ---- layer 1: bias + ascending-i chain for own board's 4 slots ----
    {
      float a[4];
      const float b1 = p.Bb[0][j];
#pragma unroll
      for (int e = 0; e < 4; ++e) a[e] = b1;
      const float* __restrict__ w1p = p.W[0] + j;
      for (int i = 0; i < 27; ++i) {
        const float w = w1p[i * HD];
#pragma unroll
        for (int e = 0; e < 4; ++e) a[e] += fs[half][e][i] * w;
      }
      float4 v;
      v.x = fmaxf(a[0], 0.f);
      v.y = fmaxf(a[1], 0.f);
      v.z = fmaxf(a[2], 0.f);
      v.w = fmaxf(a[3], 0.f);
      *(float4*)&hbufA[j * 8 + half4] = v;
    }
    __syncthreads();

    // ---- layers 2..9, specialized on active slot count ----
    const int cm = max(eCnt[0], eCnt[1]);
    if (cm == 4) run_layers<4>(p, j, half4, hbufA, hbufB);
    else if (cm == 3) run_layers<3>(p, j, half4, hbufA, hbufB);
    else if (cm == 2) run_layers<2>(p, j, half4, hbufA, hbufB);
    else if (cm == 1) run_layers<1>(p, j, half4, hbufA, hbufB);
    // after 8 layers (even # of swaps), h9 is in hbufA

    // ---- final: layer 10 + softmax + per-slot max (wave per slot) ----
    if (cm > 0) {
      const int s = tid >> 6, lane = tid & 63;
      if (s < 8) {
        const int bd = s >> 2, e = s & 3;
        if (e < eCnt[bd]) {
          float acc[ND];
#pragma unroll
          for (int jj = 0; jj < ND; ++jj) acc[jj] = 0.f;
#pragma unroll
          for (int i = 0; i < 8; ++i) {
            const int k = lane + 64 * i;
            const float hvv = hbufA[k * 8 + s];
#pragma unroll
            for (int jj = 0; jj < ND; ++jj) acc[jj] += hvv * W10s[k * ND + jj];
          }
#pragma unroll
          for (int jj = 0; jj < ND; ++jj) {
#pragma unroll
            for (int off = 32; off >= 1; off >>= 1)
              acc[jj] += __shfl_xor(acc[jj], off, 64);
          }
          if (lane == 0) {
            float lgt[ND];
#pragma unroll
            for (int jj = 0; jj < ND; ++jj) lgt[jj] = acc[jj] + p.Bb[9][jj];
            float mx = lgt[0];
            for (int jj = 1; jj < ND; ++jj) mx = fmaxf(mx, lgt[jj]);
            float e2[ND], sm = 0.f;
            for (int jj = 0; jj < ND; ++jj) {
              e2[jj] = expf(lgt[jj] - mx);
              sm += e2[jj];
            }
            float pr[ND];
            for (int jj = 0; jj < ND; ++jj) pr[jj] = e2[jj] / sm;
            const int q = lst[bd][e];
            float best = pr[0];
            int pos = 0;
            for (int jj = 1; jj < ND; ++jj)
              if (pr[jj] > best) { best = pr[jj]; pos = jj; }  // first-index tie
            float* dst = p.xpred + ((b0 + bd) * NN + q) * ND;
            for (int jj = 0; jj < ND; ++jj) dst[jj] = pr[jj];
            sMax[s] = best;
            sPos[s] = pos;
          }
        }
      }
    }
    __syncthreads();

    // ---- update: most confident slot per board (strict >, lowest q) ----
    if (tid < 2) {
      const int c = eCnt[tid];
      if (c > 0) {
        float best = sMax[tid * 4];
        int bj = 0;
        for (int jj = 1; jj < c; ++jj) {
          const float v = sMax[tid * 4 + jj];
          if (v > best) { best = v; bj = jj; }
        }
        const int q = lst[tid][bj], pos = sPos[tid * 4 + bj];
        xs[tid][q * ND + pos] = 1.0f;
      }
    }
    __syncthreads();
  }

  // ---- write final board state (output 2) ----
  for (int bd = 0; bd < 2; ++bd)
    for (int i = tid; i < BND; i += TPB)
      p.xcur[(b0 + bd) * BND + i] = xs[bd][i];
}

extern "C" void kernel_launch(void* const* d_in, const int* in_sizes, int n_in,
                              void* d_out, int out_size, void* d_ws, size_t ws_size,
                              hipStream_t stream) {
  Params prm;
  prm.x_in = (const float*)d_in[0];
  for (int i = 0; i < 10; ++i) {
    prm.W[i] = (const float*)d_in[2 + 2 * i];
    prm.Bb[i] = (const float*)d_in[3 + 2 * i];
  }
  prm.n_it = (const int*)d_in[22];
  prm.xpred = (float*)d_out;
  prm.xcur = prm.xpred + XTOT;

  fused<<<dim3(NBLK), dim3(TPB), 0, stream>>>(prm);
}